// Round 5
// baseline (383.650 us; speedup 1.0000x reference)
//
#include <hip/hip_runtime.h>
#include <hip/hip_bf16.h>

// Glm4MoeExpertLayers: x[T,H] fp32, Wgu[E,2I,H] fp32, Wdn[E,H,I] fp32, expert_idx
//   gu = x @ Wgu[e]^T ; hidden = silu(gu[:, :I]) * gu[:, I:] ; out = hidden @ Wdn[e]^T
// T=16384 H=2048 I=1536.
// R5 = R4 (counted-vmcnt 2-phase/tile pipeline, BK=32, 4 bufs, 8 waves) +
// T2 bank-conflict swizzle done both-sides-free:
//   - staging: pre-swizzled GLOBAL source col ((lane&3)^((lane>>2)&3))*8,
//     linear gload_lds dest (rule #21)
//   - read: physical chunk = l4 ^ (l15&3)  (lane-constant, zero extra VALU)
// and STAGE issued before ds_reads in each phase (T3 recipe).

namespace {

constexpr int T_ = 16384;
constexpr int H_ = 2048;
constexpr int I_ = 1536;

typedef short short8 __attribute__((ext_vector_type(8)));
typedef float f32x4 __attribute__((ext_vector_type(4)));
typedef unsigned short ushort4v __attribute__((ext_vector_type(4)));

// fp32 -> bf16 round-to-nearest-even
__device__ __forceinline__ unsigned short f2bf(float f) {
    union { float f; unsigned u; } v; v.f = f;
    return (unsigned short)((v.u + 0x7FFFu + ((v.u >> 16) & 1u)) >> 16);
}

// async global->LDS, 16B per lane. LDS dest is wave-uniform base (+lane*16 by HW).
typedef __attribute__((address_space(1))) const void gvoid;
typedef __attribute__((address_space(3))) void lvoid;
__device__ __forceinline__ void gload16(const void* g, void* l) {
    __builtin_amdgcn_global_load_lds((gvoid*)g, (lvoid*)l, 16, 0, 0);
}

#define SBAR() do { __builtin_amdgcn_s_barrier(); __builtin_amdgcn_sched_barrier(0); } while (0)
#define VMCNT4() do { asm volatile("s_waitcnt vmcnt(4)" ::: "memory"); __builtin_amdgcn_sched_barrier(0); } while (0)
#define VMCNT0() do { asm volatile("s_waitcnt vmcnt(0)" ::: "memory"); __builtin_amdgcn_sched_barrier(0); } while (0)

// ---------------------------------------------------------------------------
// fp32 -> bf16 conversion. src = base + (*eidx)*sliceElems (0 for x).
// ---------------------------------------------------------------------------
__global__ void k_cvt(const float* __restrict__ base, const int* __restrict__ eidx,
                      long sliceElems, unsigned short* __restrict__ dst, int n4) {
    const float* src = base + (size_t)(*eidx) * (size_t)sliceElems;
    int i = blockIdx.x * blockDim.x + threadIdx.x;
    const int stride = gridDim.x * blockDim.x;
    for (; i < n4; i += stride) {
        f32x4 v = ((const f32x4*)src)[i];
        ushort4v h = { f2bf(v[0]), f2bf(v[1]), f2bf(v[2]), f2bf(v[3]) };
        ((ushort4v*)dst)[i] = h;
    }
}

// ---------------------------------------------------------------------------
// GEMM1 + SwiGLU. Block: 512 thr (8 waves 2Mx4N), M-tile 256, B-rows 256
// (= gate 128 | up 128), hidden out 256x128. K over H, BK=32, NT=64.
// ---------------------------------------------------------------------------
__global__ __launch_bounds__(512, 2) void k_gemm1_swiglu(
    const unsigned short* __restrict__ xb, const unsigned short* __restrict__ wgub,
    unsigned short* __restrict__ hidden)
{
    // 4 K-tile buffers: each A[256][32] + B[256][32] bf16 = 32 KiB. Total 128 KiB.
    __shared__ unsigned short lds[4 * 16384];

    const int tid  = threadIdx.x;
    const int lane = tid & 63;
    const int wid  = tid >> 6;     // 0..7
    const int wr   = wid >> 2;     // 0..1  (M half)
    const int wc   = wid & 3;      // 0..3  (B-row quarter; 0,1=gate 2,3=up)
    const int l15  = lane & 15;
    const int l4   = lane >> 4;

    // XCD-aware bijective swizzle over 768 blocks
    const int nb = (blockIdx.x & 7) * 96 + (blockIdx.x >> 3);
    const int bx = nb % 12, by = nb / 12;
    const int m0 = by * 256;
    const int n0 = bx * 128;

    // staging: lane l writes LDS physical chunk (row rb+l/4, slot l&3);
    // pre-swizzled global col so physical slot p holds logical chunk p^(row&3).
    const int srow = lane >> 2;                                  // 0..15
    const int scol = (((lane & 3) ^ ((lane >> 2) & 3)) * 8);     // bf16 elems
    // read: logical k-chunk l4 lives at physical chunk l4^(row&3), row&3==l15&3
    const int rchunk = ((l4 ^ (l15 & 3)) * 8);                   // ushort units

    f32x4 acc[8][4];
    #pragma unroll
    for (int m = 0; m < 8; ++m)
        #pragma unroll
        for (int n = 0; n < 4; ++n) acc[m][n] = (f32x4)0.0f;

    constexpr int NT = H_ / 32;   // 64

    // ---- prologue: stage tiles 0,1 into bufs 0,1
    #pragma unroll
    for (int tt = 0; tt < 2; ++tt) {
        unsigned short* stA = lds + tt * 16384;
        unsigned short* stB = stA + 8192;
        const int kS = tt * 32;
        #pragma unroll
        for (int j = 0; j < 2; ++j) {
            const int rb = (wid * 2 + j) * 16;
            gload16(xb + (size_t)(m0 + rb + srow) * H_ + kS + scol, stA + rb * 32);
        }
        #pragma unroll
        for (int j = 0; j < 2; ++j) {
            const int rb = (wid * 2 + j) * 16;
            const int growb = (rb < 128) ? (n0 + rb) : (I_ + n0 + rb - 128);
            gload16(wgub + (size_t)(growb + srow) * H_ + kS + scol, stB + rb * 32);
        }
    }
    VMCNT4();   // tile 0 confirmed; tile 1 (4 loads) in flight
    SBAR();

    const int aoff = wr * 4096 + l15 * 32 + rchunk;   // ushort offsets
    const int boff = wc * 2048 + l15 * 32 + rchunk;

    for (int t = 0; t < NT; ++t) {
        const unsigned short* bA = lds + (t & 3) * 16384;
        const unsigned short* bB = bA + 8192;
        unsigned short* stA = lds + ((t + 2) & 3) * 16384;
        unsigned short* stB = stA + 8192;
        const int kS = (t + 2) * 32;
        const bool st = (t + 2 < NT);

        short8 bf[4], af[4];
        // ===== phase 0: stage A of tile t+2; read frags; MFMA m 0..3 =====
        if (st) {
            #pragma unroll
            for (int j = 0; j < 2; ++j) {
                const int rb = (wid * 2 + j) * 16;
                gload16(xb + (size_t)(m0 + rb + srow) * H_ + kS + scol, stA + rb * 32);
            }
        }
        #pragma unroll
        for (int n = 0; n < 4; ++n) bf[n] = *(const short8*)(bB + boff + n * 512);
        #pragma unroll
        for (int a = 0; a < 4; ++a) af[a] = *(const short8*)(bA + aoff + a * 512);
        SBAR();
        __builtin_amdgcn_s_setprio(1);
        #pragma unroll
        for (int a = 0; a < 4; ++a)
            #pragma unroll
            for (int n = 0; n < 4; ++n)
                acc[a][n] = __builtin_amdgcn_mfma_f32_16x16x32_bf16(af[a], bf[n], acc[a][n], 0, 0, 0);
        __builtin_amdgcn_s_setprio(0);
        SBAR();

        // ===== phase 1: stage B of tile t+2; read frags; MFMA m 4..7 =====
        if (st) {
            #pragma unroll
            for (int j = 0; j < 2; ++j) {
                const int rb = (wid * 2 + j) * 16;
                const int growb = (rb < 128) ? (n0 + rb) : (I_ + n0 + rb - 128);
                gload16(wgub + (size_t)(growb + srow) * H_ + kS + scol, stB + rb * 32);
            }
        }
        #pragma unroll
        for (int a = 0; a < 4; ++a) af[a] = *(const short8*)(bA + aoff + 2048 + a * 512);
        SBAR();
        __builtin_amdgcn_s_setprio(1);
        #pragma unroll
        for (int a = 0; a < 4; ++a)
            #pragma unroll
            for (int n = 0; n < 4; ++n)
                acc[4 + a][n] = __builtin_amdgcn_mfma_f32_16x16x32_bf16(af[a], bf[n], acc[4 + a][n], 0, 0, 0);
        __builtin_amdgcn_s_setprio(0);
        if (t < NT - 2)       { VMCNT4(); }   // confirms tile t+1; t+2 stays in flight
        else if (t == NT - 2) { VMCNT0(); }   // tail: confirm last tile
        SBAR();
    }

    // ---- SwiGLU cross-wave epilogue: up waves (wc>=2) -> LDS; gate waves combine.
    float* exch = (float*)lds;   // [256][128] fp32 = 128 KiB (main-loop bufs dead)
    if (wc >= 2) {
        #pragma unroll
        for (int m = 0; m < 8; ++m)
            #pragma unroll
            for (int n = 0; n < 4; ++n)
                #pragma unroll
                for (int j = 0; j < 4; ++j) {
                    const int row = wr * 128 + m * 16 + l4 * 4 + j;
                    const int col = (wc - 2) * 64 + n * 16 + l15;
                    exch[row * 128 + col] = acc[m][n][j];
                }
    }
    __syncthreads();
    if (wc < 2) {
        #pragma unroll
        for (int m = 0; m < 8; ++m)
            #pragma unroll
            for (int n = 0; n < 4; ++n)
                #pragma unroll
                for (int j = 0; j < 4; ++j) {
                    const int row = wr * 128 + m * 16 + l4 * 4 + j;
                    const int col = wc * 64 + n * 16 + l15;
                    const float g = acc[m][n][j];
                    const float u = exch[row * 128 + col];
                    const float s = g / (1.0f + __expf(-g));
                    hidden[(size_t)(m0 + row) * I_ + n0 + col] = f2bf(s * u);
                }
    }
}

// ---------------------------------------------------------------------------
// GEMM2: out[T,H] fp32 = hidden(bf16) @ wdn_bf16^T. Same pipeline, 256x256
// tile, K over I, NT=48, plain fp32 epilogue.
// ---------------------------------------------------------------------------
__global__ __launch_bounds__(512, 2) void k_gemm2(
    const unsigned short* __restrict__ hidden, const unsigned short* __restrict__ wdnb,
    float* __restrict__ out)
{
    __shared__ unsigned short lds[4 * 16384];

    const int tid  = threadIdx.x;
    const int lane = tid & 63;
    const int wid  = tid >> 6;
    const int wr   = wid >> 2;
    const int wc   = wid & 3;
    const int l15  = lane & 15;
    const int l4   = lane >> 4;

    // XCD swizzle over 512 blocks
    const int nb = (blockIdx.x & 7) * 64 + (blockIdx.x >> 3);
    const int bx = nb & 7, by = nb >> 3;
    const int m0 = by * 256;
    const int n0 = bx * 256;

    const int srow = lane >> 2;
    const int scol = (((lane & 3) ^ ((lane >> 2) & 3)) * 8);
    const int rchunk = ((l4 ^ (l15 & 3)) * 8);

    f32x4 acc[8][4];
    #pragma unroll
    for (int m = 0; m < 8; ++m)
        #pragma unroll
        for (int n = 0; n < 4; ++n) acc[m][n] = (f32x4)0.0f;

    constexpr int NT = I_ / 32;   // 48

    #pragma unroll
    for (int tt = 0; tt < 2; ++tt) {
        unsigned short* stA = lds + tt * 16384;
        unsigned short* stB = stA + 8192;
        const int kS = tt * 32;
        #pragma unroll
        for (int j = 0; j < 2; ++j) {
            const int rb = (wid * 2 + j) * 16;
            gload16(hidden + (size_t)(m0 + rb + srow) * I_ + kS + scol, stA + rb * 32);
        }
        #pragma unroll
        for (int j = 0; j < 2; ++j) {
            const int rb = (wid * 2 + j) * 16;
            gload16(wdnb + (size_t)(n0 + rb + srow) * I_ + kS + scol, stB + rb * 32);
        }
    }
    VMCNT4();
    SBAR();

    const int aoff = wr * 4096 + l15 * 32 + rchunk;
    const int boff = wc * 2048 + l15 * 32 + rchunk;

    for (int t = 0; t < NT; ++t) {
        const unsigned short* bA = lds + (t & 3) * 16384;
        const unsigned short* bB = bA + 8192;
        unsigned short* stA = lds + ((t + 2) & 3) * 16384;
        unsigned short* stB = stA + 8192;
        const int kS = (t + 2) * 32;
        const bool st = (t + 2 < NT);

        short8 bf[4], af[4];
        // phase 0
        if (st) {
            #pragma unroll
            for (int j = 0; j < 2; ++j) {
                const int rb = (wid * 2 + j) * 16;
                gload16(hidden + (size_t)(m0 + rb + srow) * I_ + kS + scol, stA + rb * 32);
            }
        }
        #pragma unroll
        for (int n = 0; n < 4; ++n) bf[n] = *(const short8*)(bB + boff + n * 512);
        #pragma unroll
        for (int a = 0; a < 4; ++a) af[a] = *(const short8*)(bA + aoff + a * 512);
        SBAR();
        __builtin_amdgcn_s_setprio(1);
        #pragma unroll
        for (int a = 0; a < 4; ++a)
            #pragma unroll
            for (int n = 0; n < 4; ++n)
                acc[a][n] = __builtin_amdgcn_mfma_f32_16x16x32_bf16(af[a], bf[n], acc[a][n], 0, 0, 0);
        __builtin_amdgcn_s_setprio(0);
        SBAR();

        // phase 1
        if (st) {
            #pragma unroll
            for (int j = 0; j < 2; ++j) {
                const int rb = (wid * 2 + j) * 16;
                gload16(wdnb + (size_t)(n0 + rb + srow) * I_ + kS + scol, stB + rb * 32);
            }
        }
        #pragma unroll
        for (int a = 0; a < 4; ++a) af[a] = *(const short8*)(bA + aoff + 2048 + a * 512);
        SBAR();
        __builtin_amdgcn_s_setprio(1);
        #pragma unroll
        for (int a = 0; a < 4; ++a)
            #pragma unroll
            for (int n = 0; n < 4; ++n)
                acc[4 + a][n] = __builtin_amdgcn_mfma_f32_16x16x32_bf16(af[a], bf[n], acc[4 + a][n], 0, 0, 0);
        __builtin_amdgcn_s_setprio(0);
        if (t < NT - 2)       { VMCNT4(); }
        else if (t == NT - 2) { VMCNT0(); }
        SBAR();
    }

    #pragma unroll
    for (int m = 0; m < 8; ++m)
        #pragma unroll
        for (int n = 0; n < 4; ++n)
            #pragma unroll
            for (int j = 0; j < 4; ++j) {
                const int row = m0 + wr * 128 + m * 16 + l4 * 4 + j;
                const int col = n0 + wc * 64 + n * 16 + l15;
                out[(size_t)row * H_ + col] = acc[m][n][j];
            }
}

} // namespace

extern "C" void kernel_launch(void* const* d_in, const int* in_sizes, int n_in,
                              void* d_out, int out_size, void* d_ws, size_t ws_size,
                              hipStream_t stream) {
    const float* x   = (const float*)d_in[0];   // [T, H]
    const float* wgu = (const float*)d_in[1];   // [E, 2I, H]
    const float* wdn = (const float*)d_in[2];   // [E, H, I]
    const int* eidx  = (const int*)d_in[3];     // [1]
    float* out = (float*)d_out;                 // [T, H]

    // d_out (134.2 MB fp32) temporarily holds xb (67.1 MB) — dead before k_gemm2
    // overwrites it (stream-serialized). ws: hidden | wgu_bf16 | wdn_bf16 = 69.2 MB.
    unsigned short* xb     = (unsigned short*)d_out;
    unsigned short* hidden = (unsigned short*)d_ws;
    unsigned short* wgub   = (unsigned short*)((char*)d_ws + 50331648);
    unsigned short* wdnb   = (unsigned short*)((char*)d_ws + 62914560);

    k_cvt<<<2048, 256, 0, stream>>>(x, eidx, 0L, xb, (T_ * H_) / 4);
    k_cvt<<<2048, 256, 0, stream>>>(wgu, eidx, (long)(2 * I_) * H_, wgub, (2 * I_ * H_) / 4);
    k_cvt<<<2048, 256, 0, stream>>>(wdn, eidx, (long)H_ * I_, wdnb, (H_ * I_) / 4);
    k_gemm1_swiglu<<<dim3((T_ / 256) * (I_ / 128)), 512, 0, stream>>>(xb, wgub, hidden);
    k_gemm2<<<dim3((T_ / 256) * (H_ / 256)), 512, 0, stream>>>(hidden, wdnb, out);
}

// Round 6
// 370.918 us; speedup vs baseline: 1.0343x; 1.0343x over previous
//
#include <hip/hip_runtime.h>
#include <hip/hip_bf16.h>

// Glm4MoeExpertLayers: x[T,H] fp32, Wgu[E,2I,H] fp32, Wdn[E,H,I] fp32, expert_idx
//   gu = x @ Wgu[e]^T ; hidden = silu(gu[:, :I]) * gu[:, I:] ; out = hidden @ Wdn[e]^T
// T=16384 H=2048 I=1536.
// R6: within-wave software pipeline. 4-buffer LDS ring (mod 4, 128 KiB), BK=32,
// 8 waves (2Mx4N), per body t: stage(t+3) -> frag ds_reads(t+1) -> 32 MFMA on
// frags(t) (register-only, overlaps the LDS reads) -> vmcnt(4) -> barrier.
// Double frag register sets, manual unroll-by-2 (no runtime-indexed frag arrays).

namespace {

constexpr int T_ = 16384;
constexpr int H_ = 2048;
constexpr int I_ = 1536;

typedef short short8 __attribute__((ext_vector_type(8)));
typedef float f32x4 __attribute__((ext_vector_type(4)));
typedef unsigned short ushort4v __attribute__((ext_vector_type(4)));

// fp32 -> bf16 round-to-nearest-even
__device__ __forceinline__ unsigned short f2bf(float f) {
    union { float f; unsigned u; } v; v.f = f;
    return (unsigned short)((v.u + 0x7FFFu + ((v.u >> 16) & 1u)) >> 16);
}
__device__ __forceinline__ float bf2f(unsigned short u) {
    union { unsigned u; float f; } v; v.u = (unsigned)u << 16;
    return v.f;
}

// async global->LDS, 16B per lane. LDS dest is wave-uniform base (+lane*16 by HW).
typedef __attribute__((address_space(1))) const void gvoid;
typedef __attribute__((address_space(3))) void lvoid;
__device__ __forceinline__ void gload16(const void* g, void* l) {
    __builtin_amdgcn_global_load_lds((gvoid*)g, (lvoid*)l, 16, 0, 0);
}

#define SBAR() do { __builtin_amdgcn_s_barrier(); __builtin_amdgcn_sched_barrier(0); } while (0)
#define VMCNT4() do { asm volatile("s_waitcnt vmcnt(4)" ::: "memory"); } while (0)
#define VMCNT0() do { asm volatile("s_waitcnt vmcnt(0)" ::: "memory"); } while (0)

// ---------------------------------------------------------------------------
// fp32 -> bf16 conversion. src = base + (*eidx)*sliceElems (0 for x).
// ---------------------------------------------------------------------------
__global__ void k_cvt(const float* __restrict__ base, const int* __restrict__ eidx,
                      long sliceElems, unsigned short* __restrict__ dst, int n4) {
    const float* src = base + (size_t)(*eidx) * (size_t)sliceElems;
    int i = blockIdx.x * blockDim.x + threadIdx.x;
    const int stride = gridDim.x * blockDim.x;
    for (; i < n4; i += stride) {
        f32x4 v = ((const f32x4*)src)[i];
        ushort4v h = { f2bf(v[0]), f2bf(v[1]), f2bf(v[2]), f2bf(v[3]) };
        ((ushort4v*)dst)[i] = h;
    }
}

// ---------------------------------------------------------------------------
// GEMM1 + SwiGLU. Block: 512 thr (8 waves 2Mx4N), M-tile 256, B-rows 256
// (gate 128 | up 128), out 256x128 hidden cols. K over H, BK=32, NT=64.
// ---------------------------------------------------------------------------
__global__ __launch_bounds__(512, 2) void k_gemm1_swiglu(
    const unsigned short* __restrict__ xb, const unsigned short* __restrict__ wgub,
    unsigned short* __restrict__ hidden)
{
    // 4 ring buffers: each A[256][32] + B[256][32] bf16 = 32 KiB. Total 128 KiB.
    __shared__ unsigned short lds[4 * 16384];

    const int tid  = threadIdx.x;
    const int lane = tid & 63;
    const int wid  = tid >> 6;     // 0..7
    const int wr   = wid >> 2;     // 0..1  (M half)
    const int wc   = wid & 3;      // 0..3  (B-row quarter; 0,1=gate 2,3=up)
    const int l15  = lane & 15;
    const int l4   = lane >> 4;

    // XCD-aware bijective swizzle over 768 blocks
    const int nb = (blockIdx.x & 7) * 96 + (blockIdx.x >> 3);
    const int bx = nb % 12, by = nb / 12;
    const int m0 = by * 256;
    const int n0 = bx * 128;

    const int srow = lane >> 2;        // staging row within 16-row chunk
    const int scol = (lane & 3) * 8;   // staging col (bf16 elems)

    f32x4 acc[8][4];
    #pragma unroll
    for (int m = 0; m < 8; ++m)
        #pragma unroll
        for (int n = 0; n < 4; ++n) acc[m][n] = (f32x4)0.0f;

    constexpr int NT = H_ / 32;   // 64

    const int aoff = wr * 4096 + l15 * 32 + l4 * 8;   // ushort offsets
    const int boff = wc * 2048 + l15 * 32 + l4 * 8;

    auto stage = [&](int s) {
        unsigned short* stA = lds + (s & 3) * 16384;
        unsigned short* stB = stA + 8192;
        const int kS = s * 32;
        #pragma unroll
        for (int j = 0; j < 2; ++j) {
            const int rb = (wid * 2 + j) * 16;
            gload16(xb + (size_t)(m0 + rb + srow) * H_ + kS + scol, stA + rb * 32);
        }
        #pragma unroll
        for (int j = 0; j < 2; ++j) {
            const int rb = (wid * 2 + j) * 16;
            const int growb = (rb < 128) ? (n0 + rb) : (I_ + n0 + rb - 128);
            gload16(wgub + (size_t)(growb + srow) * H_ + kS + scol, stB + rb * 32);
        }
    };
    auto readfrags = [&](int s, short8 (&AF)[8], short8 (&BF)[4]) {
        const unsigned short* bA = lds + (s & 3) * 16384;
        const unsigned short* bB = bA + 8192;
        #pragma unroll
        for (int a = 0; a < 8; ++a) AF[a] = *(const short8*)(bA + aoff + a * 512);
        #pragma unroll
        for (int n = 0; n < 4; ++n) BF[n] = *(const short8*)(bB + boff + n * 512);
    };
    auto body = [&](int t, short8 (&AF)[8], short8 (&BF)[4],
                    short8 (&NAF)[8], short8 (&NBF)[4]) {
        if (t + 3 < NT) stage(t + 3);
        if (t + 1 < NT) readfrags(t + 1, NAF, NBF);
        #pragma unroll
        for (int a = 0; a < 8; ++a)
            #pragma unroll
            for (int n = 0; n < 4; ++n)
                acc[a][n] = __builtin_amdgcn_mfma_f32_16x16x32_bf16(AF[a], BF[n], acc[a][n], 0, 0, 0);
        if (t + 3 < NT) { VMCNT4(); } else { VMCNT0(); }
        SBAR();
    };

    // ---- prologue: stage tiles 0,1,2; confirm 0,1; read frags(0)
    stage(0); stage(1); stage(2);
    VMCNT4();       // 12 in flight -> wait to 4: tiles 0,1 confirmed, 2 in flight
    SBAR();

    short8 afA[8], bfA[4], afB[8], bfB[4];
    readfrags(0, afA, bfA);

    for (int t = 0; t < NT; t += 2) {
        body(t,     afA, bfA, afB, bfB);
        body(t + 1, afB, bfB, afA, bfA);
    }

    // ---- SwiGLU cross-wave epilogue (bf16 exchange, 64 KiB within ring mem)
    __syncthreads();
    unsigned short* exch = lds;   // [256][128] bf16
    if (wc >= 2) {
        #pragma unroll
        for (int m = 0; m < 8; ++m)
            #pragma unroll
            for (int n = 0; n < 4; ++n)
                #pragma unroll
                for (int j = 0; j < 4; ++j) {
                    const int row = wr * 128 + m * 16 + l4 * 4 + j;
                    const int col = (wc - 2) * 64 + n * 16 + l15;
                    exch[row * 128 + col] = f2bf(acc[m][n][j]);
                }
    }
    __syncthreads();
    if (wc < 2) {
        #pragma unroll
        for (int m = 0; m < 8; ++m)
            #pragma unroll
            for (int n = 0; n < 4; ++n)
                #pragma unroll
                for (int j = 0; j < 4; ++j) {
                    const int row = wr * 128 + m * 16 + l4 * 4 + j;
                    const int col = wc * 64 + n * 16 + l15;
                    const float g = acc[m][n][j];
                    const float u = bf2f(exch[row * 128 + col]);
                    const float s = g / (1.0f + __expf(-g));
                    hidden[(size_t)(m0 + row) * I_ + n0 + col] = f2bf(s * u);
                }
    }
}

// ---------------------------------------------------------------------------
// GEMM2: out[T,H] fp32 = hidden(bf16) @ wdn_bf16^T. Same pipeline, 256x256
// tile, K over I, NT=48, plain fp32 epilogue.
// ---------------------------------------------------------------------------
__global__ __launch_bounds__(512, 2) void k_gemm2(
    const unsigned short* __restrict__ hidden, const unsigned short* __restrict__ wdnb,
    float* __restrict__ out)
{
    __shared__ unsigned short lds[4 * 16384];

    const int tid  = threadIdx.x;
    const int lane = tid & 63;
    const int wid  = tid >> 6;
    const int wr   = wid >> 2;
    const int wc   = wid & 3;
    const int l15  = lane & 15;
    const int l4   = lane >> 4;

    // XCD swizzle over 512 blocks
    const int nb = (blockIdx.x & 7) * 64 + (blockIdx.x >> 3);
    const int bx = nb & 7, by = nb >> 3;
    const int m0 = by * 256;
    const int n0 = bx * 256;

    const int srow = lane >> 2;
    const int scol = (lane & 3) * 8;

    f32x4 acc[8][4];
    #pragma unroll
    for (int m = 0; m < 8; ++m)
        #pragma unroll
        for (int n = 0; n < 4; ++n) acc[m][n] = (f32x4)0.0f;

    constexpr int NT = I_ / 32;   // 48

    const int aoff = wr * 4096 + l15 * 32 + l4 * 8;
    const int boff = wc * 2048 + l15 * 32 + l4 * 8;

    auto stage = [&](int s) {
        unsigned short* stA = lds + (s & 3) * 16384;
        unsigned short* stB = stA + 8192;
        const int kS = s * 32;
        #pragma unroll
        for (int j = 0; j < 2; ++j) {
            const int rb = (wid * 2 + j) * 16;
            gload16(hidden + (size_t)(m0 + rb + srow) * I_ + kS + scol, stA + rb * 32);
        }
        #pragma unroll
        for (int j = 0; j < 2; ++j) {
            const int rb = (wid * 2 + j) * 16;
            gload16(wdnb + (size_t)(n0 + rb + srow) * I_ + kS + scol, stB + rb * 32);
        }
    };
    auto readfrags = [&](int s, short8 (&AF)[8], short8 (&BF)[4]) {
        const unsigned short* bA = lds + (s & 3) * 16384;
        const unsigned short* bB = bA + 8192;
        #pragma unroll
        for (int a = 0; a < 8; ++a) AF[a] = *(const short8*)(bA + aoff + a * 512);
        #pragma unroll
        for (int n = 0; n < 4; ++n) BF[n] = *(const short8*)(bB + boff + n * 512);
    };
    auto body = [&](int t, short8 (&AF)[8], short8 (&BF)[4],
                    short8 (&NAF)[8], short8 (&NBF)[4]) {
        if (t + 3 < NT) stage(t + 3);
        if (t + 1 < NT) readfrags(t + 1, NAF, NBF);
        #pragma unroll
        for (int a = 0; a < 8; ++a)
            #pragma unroll
            for (int n = 0; n < 4; ++n)
                acc[a][n] = __builtin_amdgcn_mfma_f32_16x16x32_bf16(AF[a], BF[n], acc[a][n], 0, 0, 0);
        if (t + 3 < NT) { VMCNT4(); } else { VMCNT0(); }
        SBAR();
    };

    stage(0); stage(1); stage(2);
    VMCNT4();
    SBAR();

    short8 afA[8], bfA[4], afB[8], bfB[4];
    readfrags(0, afA, bfA);

    for (int t = 0; t < NT; t += 2) {
        body(t,     afA, bfA, afB, bfB);
        body(t + 1, afB, bfB, afA, bfA);
    }

    #pragma unroll
    for (int m = 0; m < 8; ++m)
        #pragma unroll
        for (int n = 0; n < 4; ++n)
            #pragma unroll
            for (int j = 0; j < 4; ++j) {
                const int row = m0 + wr * 128 + m * 16 + l4 * 4 + j;
                const int col = n0 + wc * 64 + n * 16 + l15;
                out[(size_t)row * H_ + col] = acc[m][n][j];
            }
}

} // namespace

extern "C" void kernel_launch(void* const* d_in, const int* in_sizes, int n_in,
                              void* d_out, int out_size, void* d_ws, size_t ws_size,
                              hipStream_t stream) {
    const float* x   = (const float*)d_in[0];   // [T, H]
    const float* wgu = (const float*)d_in[1];   // [E, 2I, H]
    const float* wdn = (const float*)d_in[2];   // [E, H, I]
    const int* eidx  = (const int*)d_in[3];     // [1]
    float* out = (float*)d_out;                 // [T, H]

    // d_out (134.2 MB fp32) temporarily holds xb (67.1 MB) — dead before k_gemm2
    // overwrites it (stream-serialized). ws: hidden | wgu_bf16 | wdn_bf16 = 69.2 MB.
    unsigned short* xb     = (unsigned short*)d_out;
    unsigned short* hidden = (unsigned short*)d_ws;
    unsigned short* wgub   = (unsigned short*)((char*)d_ws + 50331648);
    unsigned short* wdnb   = (unsigned short*)((char*)d_ws + 62914560);

    k_cvt<<<2048, 256, 0, stream>>>(x, eidx, 0L, xb, (T_ * H_) / 4);
    k_cvt<<<2048, 256, 0, stream>>>(wgu, eidx, (long)(2 * I_) * H_, wgub, (2 * I_ * H_) / 4);
    k_cvt<<<2048, 256, 0, stream>>>(wdn, eidx, (long)H_ * I_, wdnb, (H_ * I_) / 4);
    k_gemm1_swiglu<<<dim3((T_ / 256) * (I_ / 128)), 512, 0, stream>>>(xb, wgub, hidden);
    k_gemm2<<<dim3((T_ / 256) * (H_ / 256)), 512, 0, stream>>>(hidden, wdnb, out);
}